// Round 1
// baseline (378.807 us; speedup 1.0000x reference)
//
#include <hip/hip_runtime.h>
#include <cstdint>

using u16 = unsigned short;
using u32 = unsigned int;

constexpr int kB  = 4096;  // batch
constexpr int kE  = 512;   // embeddings (K)
constexpr int kT  = 32;    // tokens
constexpr int kH  = 256;   // hidden (N)
constexpr int kIT = 5;     // inhibition iterations
constexpr float kEPS = 1e-6f;

typedef __attribute__((ext_vector_type(8))) short short8;
typedef __attribute__((ext_vector_type(4))) float floatx4;
typedef __attribute__((ext_vector_type(8))) u16 ushort8;

__device__ __forceinline__ u16 f2bf(float f) {
  u32 u = __builtin_bit_cast(u32, f);
  u32 r = (u + 0x7fffu + ((u >> 16) & 1u)) >> 16;  // round-to-nearest-even
  return (u16)r;
}

// async global->LDS, 16B per lane; LDS dest = uniform base + lane*16
__device__ __forceinline__ void gl_lds16(const void* g, void* l) {
  __builtin_amdgcn_global_load_lds(
      (__attribute__((address_space(1))) void*)(g),
      (__attribute__((address_space(3))) void*)(l), 16, 0, 0);
}

// ---------------- prepass: x fp32 -> bf16 ----------------
__global__ void cvt_x_kernel(const float* __restrict__ x, u16* __restrict__ xb) {
  const int i = (blockIdx.x * 256 + threadIdx.x) * 8;
  const float4 a = *(const float4*)(x + i);
  const float4 b = *(const float4*)(x + i + 4);
  ushort8 o;
  o[0] = f2bf(a.x); o[1] = f2bf(a.y); o[2] = f2bf(a.z); o[3] = f2bf(a.w);
  o[4] = f2bf(b.x); o[5] = f2bf(b.y); o[6] = f2bf(b.z); o[7] = f2bf(b.w);
  *(ushort8*)(xb + i) = o;
}

// ---------------- prepass: w [T][E][H] fp32 -> wT [T][H][E] bf16 ----------------
__global__ void transpose_w_kernel(const float* __restrict__ w, u16* __restrict__ wt) {
  __shared__ float tile[32][33];
  const int t  = blockIdx.z;
  const int e0 = blockIdx.x * 32;
  const int h0 = blockIdx.y * 32;
  const int tx = threadIdx.x & 31;
  const int ty = threadIdx.x >> 5;  // 0..7
  const float* wp = w + (size_t)t * kE * kH;
#pragma unroll
  for (int r = 0; r < 32; r += 8)
    tile[ty + r][tx] = wp[(size_t)(e0 + ty + r) * kH + h0 + tx];
  __syncthreads();
  u16* op = wt + (size_t)t * kH * kE;
#pragma unroll
  for (int r = 0; r < 32; r += 8)
    op[(size_t)(h0 + ty + r) * kE + e0 + tx] = f2bf(tile[tx][ty + r]);
}

// ---------------- fused: dual GEMM + inhibition + gate + LayerNorm ----------------
// block = 64 batch rows x one token t x full H=256. 4 waves, wave w -> rows [w*16,+16).
__global__ __launch_bounds__(256) void fused_kernel(
    const u16* __restrict__ xb, const u16* __restrict__ wti, const u16* __restrict__ wtv,
    const float* __restrict__ alphas, const float* __restrict__ scales,
    const float* __restrict__ gamma, const float* __restrict__ beta,
    float* __restrict__ out) {
  __shared__ __attribute__((aligned(16))) u16 Al[64 * 32];    // A tile [64 rows][BK=32]
  __shared__ __attribute__((aligned(16))) u16 Bi[256 * 32];   // W_in^T tile [n=256][k=32]
  __shared__ __attribute__((aligned(16))) u16 Bv[256 * 32];   // W_val^T tile

  const int tid  = threadIdx.x;
  const int wv   = tid >> 6;
  const int lane = tid & 63;
  const int l15  = lane & 15;
  const int quad = lane >> 4;

  const int t    = blockIdx.x >> 6;          // 64 row-blocks per token
  const int row0 = (blockIdx.x & 63) * 64;

  // staging: lane covers 16B = 8 bf16; 4 lanes per 64B row-chunk
  const int lr = lane >> 2;        // row within 16-row chunk
  const int lc = (lane & 3) * 8;   // elem offset within 32-elem row

  const u16* xg  = xb  + (size_t)(row0 + wv * 16 + lr) * kE + lc;
  const u16* big = wti + (size_t)t * kH * kE + (size_t)(wv * 64 + lr) * kE + lc;
  const u16* bvg = wtv + (size_t)t * kH * kE + (size_t)(wv * 64 + lr) * kE + lc;
  u16* Al_dst = Al + wv * 512;    // wave stages 16 rows = 1KB
  u16* Bi_dst = Bi + wv * 2048;   // wave stages 64 rows = 4KB (4 chunks)
  u16* Bv_dst = Bv + wv * 2048;

  floatx4 acc_i[16], acc_v[16];
#pragma unroll
  for (int nt = 0; nt < 16; ++nt) { acc_i[nt] = (floatx4)0.0f; acc_v[nt] = (floatx4)0.0f; }

  // fragment read pointers (A: m=l15 row, k contiguous; B: n=l15 row of [n][k] layout)
  const u16* afp = Al + (wv * 16 + l15) * 32 + quad * 8;
  const u16* bip = Bi + l15 * 32 + quad * 8;
  const u16* bvp = Bv + l15 * 32 + quad * 8;

  for (int ko = 0; ko < kE / 32; ++ko) {
    const int goff = ko * 32;
    __syncthreads();  // previous tile fully consumed
    gl_lds16(xg + goff, Al_dst);
#pragma unroll
    for (int c = 0; c < 4; ++c) {
      gl_lds16(big + (size_t)c * 16 * kE + goff, Bi_dst + c * 512);
      gl_lds16(bvg + (size_t)c * 16 * kE + goff, Bv_dst + c * 512);
    }
    __syncthreads();  // drains vmcnt(0): async LDS loads landed

    const short8 af = *(const short8*)(afp);
#pragma unroll
    for (int nt = 0; nt < 16; ++nt) {
      const short8 bf = *(const short8*)(bip + nt * 512);
      const short8 bv = *(const short8*)(bvp + nt * 512);
      acc_i[nt] = __builtin_amdgcn_mfma_f32_16x16x32_bf16(af, bf, acc_i[nt], 0, 0, 0);
      acc_v[nt] = __builtin_amdgcn_mfma_f32_16x16x32_bf16(af, bv, acc_v[nt], 0, 0, 0);
    }
  }

  // ---- epilogue, fully in-wave. C layout: col = nt*16 + l15, row = quad*4 + r ----
  const float inv_h = 1.0f / kH;

#pragma unroll
  for (int nt = 0; nt < 16; ++nt)
#pragma unroll
    for (int r = 0; r < 4; ++r)
      acc_i[nt][r] = fmaxf(acc_i[nt][r], 0.0f);

#pragma unroll
  for (int it = 0; it < kIT; ++it) {
    float s[4] = {0.f, 0.f, 0.f, 0.f};
#pragma unroll
    for (int nt = 0; nt < 16; ++nt)
#pragma unroll
      for (int r = 0; r < 4; ++r) s[r] += acc_i[nt][r];
#pragma unroll
    for (int r = 0; r < 4; ++r)
#pragma unroll
      for (int off = 1; off < 16; off <<= 1)
        s[r] += __shfl_xor(s[r], off, 16);  // reduce 16 lanes of the quad
    const float a = alphas[t * kIT + it] * inv_h;
#pragma unroll
    for (int nt = 0; nt < 16; ++nt)
#pragma unroll
      for (int r = 0; r < 4; ++r)
        acc_i[nt][r] = fmaxf(acc_i[nt][r] - a * s[r], 0.0f);
  }

  float sum[4] = {0.f, 0.f, 0.f, 0.f}, ssq[4] = {0.f, 0.f, 0.f, 0.f};
#pragma unroll
  for (int nt = 0; nt < 16; ++nt) {
    const int col = nt * 16 + l15;
    const float sc = scales[t * kH + col];
#pragma unroll
    for (int r = 0; r < 4; ++r) {
      const float v = sc * acc_i[nt][r] * acc_v[nt][r];
      acc_v[nt][r] = v;
      sum[r] += v;
      ssq[r] += v * v;
    }
  }
#pragma unroll
  for (int r = 0; r < 4; ++r)
#pragma unroll
    for (int off = 1; off < 16; off <<= 1) {
      sum[r] += __shfl_xor(sum[r], off, 16);
      ssq[r] += __shfl_xor(ssq[r], off, 16);
    }

  float mu[4], rs[4];
#pragma unroll
  for (int r = 0; r < 4; ++r) {
    mu[r] = sum[r] * inv_h;
    const float var = ssq[r] * inv_h - mu[r] * mu[r];
    rs[r] = rsqrtf(var + kEPS);
  }

  float* orow = out + (size_t)(row0 + wv * 16 + quad * 4) * (kT * kH) + (size_t)t * kH;
#pragma unroll
  for (int nt = 0; nt < 16; ++nt) {
    const int col = nt * 16 + l15;
    const float g  = gamma[t * kH + col];
    const float be = beta[t * kH + col];
#pragma unroll
    for (int r = 0; r < 4; ++r)
      orow[(size_t)r * kT * kH + col] = (acc_v[nt][r] - mu[r]) * rs[r] * g + be;
  }
}

extern "C" void kernel_launch(void* const* d_in, const int* in_sizes, int n_in,
                              void* d_out, int out_size, void* d_ws, size_t ws_size,
                              hipStream_t stream) {
  const float* x      = (const float*)d_in[0];
  const float* w_in   = (const float*)d_in[1];
  const float* w_val  = (const float*)d_in[2];
  const float* alphas = (const float*)d_in[3];
  const float* scales = (const float*)d_in[4];
  const float* gamma  = (const float*)d_in[5];
  const float* beta   = (const float*)d_in[6];
  float* out = (float*)d_out;

  // workspace layout: x_bf16 (4MB) | W_in^T bf16 (8MB) | W_val^T bf16 (8MB)
  u16* xb  = (u16*)d_ws;
  u16* wti = xb + (size_t)kB * kE;
  u16* wtv = wti + (size_t)kT * kH * kE;

  cvt_x_kernel<<<(kB * kE) / (256 * 8), 256, 0, stream>>>(x, xb);
  dim3 tg(kE / 32, kH / 32, kT);
  transpose_w_kernel<<<tg, 256, 0, stream>>>(w_in, wti);
  transpose_w_kernel<<<tg, 256, 0, stream>>>(w_val, wtv);
  fused_kernel<<<kT * (kB / 64), 256, 0, stream>>>(xb, wti, wtv, alphas, scales,
                                                   gamma, beta, out);
}

// Round 2
// 358.127 us; speedup vs baseline: 1.0577x; 1.0577x over previous
//
#include <hip/hip_runtime.h>
#include <cstdint>

using u16 = unsigned short;
using u32 = unsigned int;

constexpr int kB  = 4096;
constexpr int kE  = 512;
constexpr int kT  = 32;
constexpr int kH  = 256;
constexpr int kIT = 5;
constexpr float kEPS = 1e-6f;

typedef __attribute__((ext_vector_type(8)))  short short8;
typedef __attribute__((ext_vector_type(16))) float floatx16;
typedef __attribute__((ext_vector_type(8)))  u16   ushort8;

__device__ __forceinline__ u16 f2bf(float f) {
  u32 u = __builtin_bit_cast(u32, f);
  u32 r = (u + 0x7fffu + ((u >> 16) & 1u)) >> 16;
  return (u16)r;
}

__device__ __forceinline__ void gl_lds16(const void* g, void* l) {
  __builtin_amdgcn_global_load_lds(
      (__attribute__((address_space(1))) void*)(g),
      (__attribute__((address_space(3))) void*)(l), 16, 0, 0);
}

__device__ __forceinline__ floatx16 mfma32(short8 a, short8 b, floatx16 c) {
  return __builtin_amdgcn_mfma_f32_32x32x16_bf16(a, b, c, 0, 0, 0);
}

// ---- prepass: x fp32 -> bf16, 16B chunks rotated by (row>>1)&3 within 64B groups
__global__ void cvt_x_kernel(const float* __restrict__ x, u16* __restrict__ xb) {
  const int idx = blockIdx.x * 256 + threadIdx.x;   // one 8-elem chunk per thread
  const int b = idx >> 6, c = idx & 63;
  const float4 a = *(const float4*)(x + (size_t)b * kE + c * 8);
  const float4 d = *(const float4*)(x + (size_t)b * kE + c * 8 + 4);
  ushort8 o;
  o[0]=f2bf(a.x); o[1]=f2bf(a.y); o[2]=f2bf(a.z); o[3]=f2bf(a.w);
  o[4]=f2bf(d.x); o[5]=f2bf(d.y); o[6]=f2bf(d.z); o[7]=f2bf(d.w);
  const int ko = c >> 2, j = c & 3;
  const int pp = (j + ((b >> 1) & 3)) & 3;
  *(ushort8*)(xb + (size_t)b * kE + ko * 32 + pp * 8) = o;
}

// ---- prepass: w [T][E][H] fp32 -> wT [T][H][E] bf16, same chunk rotation by (n>>1)&3
__global__ __launch_bounds__(256) void transpose_w_kernel(const float* __restrict__ w,
                                                          u16* __restrict__ wt) {
  __shared__ float tile[64 * 65];
  const int t  = blockIdx.z;
  const int h0 = blockIdx.x * 64;
  const int e0 = blockIdx.y * 64;
  const int tid = threadIdx.x;
  const float* wp = w + (size_t)t * kE * kH + (size_t)e0 * kH + h0;
  const int hr = (tid & 15) * 4, er = tid >> 4;
#pragma unroll
  for (int p = 0; p < 4; ++p) {
    const int e = er + p * 16;
    const float4 v = *(const float4*)(wp + (size_t)e * kH + hr);
    tile[e * 65 + hr + 0] = v.x; tile[e * 65 + hr + 1] = v.y;
    tile[e * 65 + hr + 2] = v.z; tile[e * 65 + hr + 3] = v.w;
  }
  __syncthreads();
  u16* op = wt + (size_t)t * kH * kE;
  const int c = tid & 7, nl = tid >> 3;  // nl 0..31
#pragma unroll
  for (int p = 0; p < 2; ++p) {
    const int n  = nl + p * 32;
    const int ng = h0 + n;
    ushort8 o;
#pragma unroll
    for (int i = 0; i < 8; ++i) o[i] = f2bf(tile[(c * 8 + i) * 65 + n]);
    const int ko = (e0 >> 5) + (c >> 2);
    const int pp = ((c & 3) + ((ng >> 1) & 3)) & 3;
    *(ushort8*)(op + (size_t)ng * kE + ko * 32 + pp * 8) = o;
  }
}

// ---- fused: dual GEMM (32x32x16 MFMA) + inhibition + gate + LayerNorm ----
// block = 64 rows x 256 cols, 4 waves n-split; wave tile 64x64 (2mt x 2nt).
__global__ __launch_bounds__(256, 3) void fused_kernel(
    const u16* __restrict__ xb, const u16* __restrict__ wti, const u16* __restrict__ wtv,
    const float* __restrict__ alphas, const float* __restrict__ scales,
    const float* __restrict__ gamma, const float* __restrict__ beta,
    float* __restrict__ out) {
  __shared__ __attribute__((aligned(16))) u16 Al[64 * 32];    // 4KB
  __shared__ __attribute__((aligned(16))) u16 Bi[256 * 32];   // 16KB
  __shared__ __attribute__((aligned(16))) u16 Bv[256 * 32];   // 16KB
  __shared__ __attribute__((aligned(16))) float redA[64 * 4];
  __shared__ __attribute__((aligned(16))) float redB[64 * 4];
  __shared__ __attribute__((aligned(16))) float smu[64];
  __shared__ __attribute__((aligned(16))) float sinv[64];

  const int tid  = threadIdx.x;
  const int wv   = tid >> 6;
  const int lane = tid & 63;
  const int l31  = lane & 31;
  const int h    = lane >> 5;

  // token-clustered swizzle: co-resident blocks on an XCD share t
  const int bi_ = blockIdx.x;
  const int g_  = bi_ >> 8, r_ = bi_ & 255;
  const int t     = (g_ << 2) | ((r_ >> 3) & 3);
  const int row0  = (((r_ >> 5) << 3) | (r_ & 7)) * 64;

  // staging: lane covers 16B; lr = row within 16-row chunk, lp = physical 16B chunk
  const int lr = lane >> 2, lp = lane & 3;
  const u16* xg  = xb + (size_t)(row0 + wv * 16 + lr) * kE + lp * 8;
  const size_t wb = (size_t)t * kH * kE + (size_t)(wv * 64 + lr) * kE + lp * 8;
  const u16* big = wti + wb;
  const u16* bvg = wtv + wb;
  u16* Al_dst = Al + wv * (16 * 32);
  u16* Bi_dst = Bi + wv * (64 * 32);
  u16* Bv_dst = Bv + wv * (64 * 32);

  floatx16 ai[2][2], av[2][2];
#pragma unroll
  for (int mt = 0; mt < 2; ++mt)
#pragma unroll
    for (int nt = 0; nt < 2; ++nt) { ai[mt][nt] = (floatx16)0.f; av[mt][nt] = (floatx16)0.f; }

  const int rot = (l31 >> 1) & 3;

  for (int ko = 0; ko < kE / 32; ++ko) {
    const int go = ko * 32;
    __syncthreads();
    gl_lds16(xg + go, Al_dst);
#pragma unroll
    for (int c = 0; c < 4; ++c) {
      gl_lds16(big + (size_t)c * 16 * kE + go, Bi_dst + c * (16 * 32));
      gl_lds16(bvg + (size_t)c * 16 * kE + go, Bv_dst + c * (16 * 32));
    }
    __syncthreads();
#pragma unroll
    for (int s = 0; s < 2; ++s) {
      const int p = ((s * 2 + h) + rot) & 3;
      const short8 a0 = *(const short8*)(Al + l31 * 32 + p * 8);
      const short8 a1 = *(const short8*)(Al + (32 + l31) * 32 + p * 8);
      {
        const short8 b0 = *(const short8*)(Bi + (wv * 64 + l31) * 32 + p * 8);
        ai[0][0] = mfma32(a0, b0, ai[0][0]);
        ai[1][0] = mfma32(a1, b0, ai[1][0]);
      }
      {
        const short8 b1 = *(const short8*)(Bi + (wv * 64 + 32 + l31) * 32 + p * 8);
        ai[0][1] = mfma32(a0, b1, ai[0][1]);
        ai[1][1] = mfma32(a1, b1, ai[1][1]);
      }
      {
        const short8 b0 = *(const short8*)(Bv + (wv * 64 + l31) * 32 + p * 8);
        av[0][0] = mfma32(a0, b0, av[0][0]);
        av[1][0] = mfma32(a1, b0, av[1][0]);
      }
      {
        const short8 b1 = *(const short8*)(Bv + (wv * 64 + 32 + l31) * 32 + p * 8);
        av[0][1] = mfma32(a0, b1, av[0][1]);
        av[1][1] = mfma32(a1, b1, av[1][1]);
      }
    }
  }

  // ---- epilogue. C layout (32x32): col = l31 (+nt*32+wv*64), row = (reg&3)+8*(reg>>2)+4*h (+mt*32)
  const float inv_h = 1.0f / kH;
  float al[kIT];
#pragma unroll
  for (int i = 0; i < kIT; ++i) al[i] = alphas[t * kIT + i] * inv_h;

#pragma unroll
  for (int mt = 0; mt < 2; ++mt)
#pragma unroll
    for (int nt = 0; nt < 2; ++nt)
#pragma unroll
      for (int q = 0; q < 16; ++q) ai[mt][nt][q] = fmaxf(ai[mt][nt][q], 0.f);

  for (int it = 0; it < kIT; ++it) {
#pragma unroll
    for (int mt = 0; mt < 2; ++mt)
#pragma unroll
      for (int q = 0; q < 16; ++q) {
        float v = ai[mt][0][q] + ai[mt][1][q];
        v += __shfl_xor(v, 1, 32);
        v += __shfl_xor(v, 2, 32);
        v += __shfl_xor(v, 4, 32);
        v += __shfl_xor(v, 8, 32);
        v += __shfl_xor(v, 16, 32);
        if (l31 == q)
          redA[(mt * 32 + (q & 3) + 8 * (q >> 2) + 4 * h) * 4 + wv] = v;
      }
    __syncthreads();
    if (tid < 64) {
      const float4 q4 = *(const float4*)(redA + tid * 4);
      smu[tid] = q4.x + q4.y + q4.z + q4.w;   // row sum
    }
    __syncthreads();
    const float am = al[it];
#pragma unroll
    for (int mt = 0; mt < 2; ++mt)
#pragma unroll
      for (int g4 = 0; g4 < 4; ++g4) {
        const float4 ms = *(const float4*)(smu + mt * 32 + 4 * h + 8 * g4);
#pragma unroll
        for (int rr = 0; rr < 4; ++rr) {
          const int q = g4 * 4 + rr;
          ai[mt][0][q] = fmaxf(ai[mt][0][q] - am * ms[rr], 0.f);
          ai[mt][1][q] = fmaxf(ai[mt][1][q] - am * ms[rr], 0.f);
        }
      }
    __syncthreads();
  }

  // gate + LN stats
  const float sc0 = scales[t * kH + wv * 64 + l31];
  const float sc1 = scales[t * kH + wv * 64 + 32 + l31];
#pragma unroll
  for (int mt = 0; mt < 2; ++mt)
#pragma unroll
    for (int q = 0; q < 16; ++q) {
      const float v0 = sc0 * ai[mt][0][q] * av[mt][0][q];
      const float v1 = sc1 * ai[mt][1][q] * av[mt][1][q];
      av[mt][0][q] = v0; av[mt][1][q] = v1;
      float s = v0 + v1, qq = v0 * v0 + v1 * v1;
      s += __shfl_xor(s, 1, 32);  qq += __shfl_xor(qq, 1, 32);
      s += __shfl_xor(s, 2, 32);  qq += __shfl_xor(qq, 2, 32);
      s += __shfl_xor(s, 4, 32);  qq += __shfl_xor(qq, 4, 32);
      s += __shfl_xor(s, 8, 32);  qq += __shfl_xor(qq, 8, 32);
      s += __shfl_xor(s, 16, 32); qq += __shfl_xor(qq, 16, 32);
      if (l31 == q) {
        const int row = mt * 32 + (q & 3) + 8 * (q >> 2) + 4 * h;
        redA[row * 4 + wv] = s;
        redB[row * 4 + wv] = qq;
      }
    }
  __syncthreads();
  if (tid < 64) {
    const float4 s4 = *(const float4*)(redA + tid * 4);
    const float4 q4 = *(const float4*)(redB + tid * 4);
    const float sum = s4.x + s4.y + s4.z + s4.w;
    const float ssq = q4.x + q4.y + q4.z + q4.w;
    const float mu  = sum * inv_h;
    const float var = ssq * inv_h - mu * mu;
    smu[tid]  = mu;
    sinv[tid] = rsqrtf(var + kEPS);
  }
  __syncthreads();

  const float g0 = gamma[t * kH + wv * 64 + l31];
  const float g1 = gamma[t * kH + wv * 64 + 32 + l31];
  const float b0 = beta[t * kH + wv * 64 + l31];
  const float b1 = beta[t * kH + wv * 64 + 32 + l31];
  float* outp = out + (size_t)row0 * kT * kH + (size_t)t * kH + wv * 64 + l31;
#pragma unroll
  for (int mt = 0; mt < 2; ++mt)
#pragma unroll
    for (int g4 = 0; g4 < 4; ++g4) {
      const float4 mu4 = *(const float4*)(smu + mt * 32 + 4 * h + 8 * g4);
      const float4 iv4 = *(const float4*)(sinv + mt * 32 + 4 * h + 8 * g4);
#pragma unroll
      for (int rr = 0; rr < 4; ++rr) {
        const int q   = g4 * 4 + rr;
        const int row = mt * 32 + rr + 8 * g4 + 4 * h;
        outp[(size_t)row * kT * kH]      = (av[mt][0][q] - mu4[rr]) * iv4[rr] * g0 + b0;
        outp[(size_t)row * kT * kH + 32] = (av[mt][1][q] - mu4[rr]) * iv4[rr] * g1 + b1;
      }
    }
}

extern "C" void kernel_launch(void* const* d_in, const int* in_sizes, int n_in,
                              void* d_out, int out_size, void* d_ws, size_t ws_size,
                              hipStream_t stream) {
  const float* x      = (const float*)d_in[0];
  const float* w_in   = (const float*)d_in[1];
  const float* w_val  = (const float*)d_in[2];
  const float* alphas = (const float*)d_in[3];
  const float* scales = (const float*)d_in[4];
  const float* gamma  = (const float*)d_in[5];
  const float* beta   = (const float*)d_in[6];
  float* out = (float*)d_out;

  u16* xb  = (u16*)d_ws;
  u16* wti = xb + (size_t)kB * kE;
  u16* wtv = wti + (size_t)kT * kH * kE;

  cvt_x_kernel<<<(kB * kE / 8) / 256, 256, 0, stream>>>(x, xb);
  dim3 tg(kH / 64, kE / 64, kT);
  transpose_w_kernel<<<tg, 256, 0, stream>>>(w_in, wti);
  transpose_w_kernel<<<tg, 256, 0, stream>>>(w_val, wtv);
  fused_kernel<<<kT * (kB / 64), 256, 0, stream>>>(xb, wti, wtv, alphas, scales,
                                                   gamma, beta, out);
}

// Round 4
// 357.391 us; speedup vs baseline: 1.0599x; 1.0021x over previous
//
#include <hip/hip_runtime.h>
#include <cstdint>

using u16 = unsigned short;
using u32 = unsigned int;

constexpr int kB  = 4096;
constexpr int kE  = 512;
constexpr int kT  = 32;
constexpr int kH  = 256;
constexpr int kIT = 5;
constexpr float kEPS = 1e-6f;

typedef __attribute__((ext_vector_type(8)))  short short8;
typedef __attribute__((ext_vector_type(16))) float floatx16;
typedef __attribute__((ext_vector_type(8)))  u16   ushort8;

__device__ __forceinline__ u16 f2bf(float f) {
  u32 u = __builtin_bit_cast(u32, f);
  return (u16)((u + 0x7fffu + ((u >> 16) & 1u)) >> 16);
}

__device__ __forceinline__ floatx16 mfma32(short8 a, short8 b, floatx16 c) {
  return __builtin_amdgcn_mfma_f32_32x32x16_bf16(a, b, c, 0, 0, 0);
}

// ---------------- combined prepass: pack x and both W into fragment-major bf16 ----
// xp chunk c = slab*64 + ks*2 + mt : lane l holds row=slab*64+mt*32+(l&31), k=ks*16+(l>>5)*8+j
// wp chunk c = t*512 + ks*16 + ntile*2 + mat : lane l holds n=ntile*32+(l&31), k=ks*16+(l>>5)*8+j
__global__ __launch_bounds__(256) void pack_kernel(
    const float* __restrict__ x, const float* __restrict__ w_in,
    const float* __restrict__ w_val, u16* __restrict__ xp, u16* __restrict__ wp) {
  const int bid = blockIdx.x;
  if (bid < 1024) {
    const int gt = bid * 256 + threadIdx.x;
    const int lane = gt & 63, c = gt >> 6;
    const int mt = c & 1, ks = (c >> 1) & 31, slab = c >> 6;
    const int row = slab * 64 + mt * 32 + (lane & 31);
    const int k   = ks * 16 + (lane >> 5) * 8;
    const float4 f0 = *(const float4*)(x + (size_t)row * kE + k);
    const float4 f1 = *(const float4*)(x + (size_t)row * kE + k + 4);
    ushort8 o;
    o[0] = f2bf(f0.x); o[1] = f2bf(f0.y); o[2] = f2bf(f0.z); o[3] = f2bf(f0.w);
    o[4] = f2bf(f1.x); o[5] = f2bf(f1.y); o[6] = f2bf(f1.z); o[7] = f2bf(f1.w);
    *(ushort8*)(xp + (size_t)c * 512 + lane * 8) = o;
  } else {
    const int gt = (bid - 1024) * 256 + threadIdx.x;
    const int lane = gt & 63, c = gt >> 6;
    const int mat = c & 1, ntile = (c >> 1) & 7, ks = (c >> 4) & 31, t = c >> 9;
    const int n = ntile * 32 + (lane & 31);
    const int k = ks * 16 + (lane >> 5) * 8;
    const float* src = (mat ? w_val : w_in) + (size_t)t * kE * kH;
    ushort8 o;
#pragma unroll
    for (int j = 0; j < 8; ++j) o[j] = f2bf(src[(size_t)(k + j) * kH + n]);
    *(ushort8*)(wp + (size_t)c * 512 + lane * 8) = o;
  }
}

// ---------------- fused: barrier-free K-loop, direct coalesced fragment loads ----
// block = 64 rows x 256 cols; 4 waves n-split; wave tile 64x64 (2mt x 2nt), dual GEMM.
__global__ __launch_bounds__(256) void fused_kernel(
    const u16* __restrict__ xp, const u16* __restrict__ wp,
    const float* __restrict__ alphas, const float* __restrict__ scales,
    const float* __restrict__ gamma, const float* __restrict__ beta,
    float* __restrict__ out) {
  __shared__ __attribute__((aligned(16))) float sAcc[32 * 256];  // 32KB

  const int tid  = threadIdx.x;
  const int wv   = tid >> 6;
  const int lane = tid & 63;
  const int l31  = lane & 31;
  const int h    = lane >> 5;

  // token-clustered swizzle: per XCD, 8 consecutive blocks share t; all 64 blocks
  // of token t dispatch contiguously (W slice 512KB stays L2-hot).
  const int bid  = blockIdx.x;
  const int xcd  = bid & 7, j_ = bid >> 3;
  const int t    = j_ >> 3;
  const int slab = ((j_ & 7) << 3) | xcd;

  const u16* xpb = xp + (size_t)slab * (32 * 2 * 512) + lane * 8;
  const u16* wpb = wp + (size_t)t * (32 * 16 * 512) + (size_t)(wv * 2) * 1024 + lane * 8;

  floatx16 ai[2][2], av[2][2];
#pragma unroll
  for (int m = 0; m < 2; ++m)
#pragma unroll
    for (int n = 0; n < 2; ++n) { ai[m][n] = (floatx16)0.f; av[m][n] = (floatx16)0.f; }

  short8 A[2][2], BI[2][2], BV[2][2];
  A[0][0]  = *(const short8*)(xpb);
  A[0][1]  = *(const short8*)(xpb + 512);
  BI[0][0] = *(const short8*)(wpb);
  BV[0][0] = *(const short8*)(wpb + 512);
  BI[0][1] = *(const short8*)(wpb + 1024);
  BV[0][1] = *(const short8*)(wpb + 1536);

#pragma unroll
  for (int ks = 0; ks < 32; ++ks) {
    const int cur = ks & 1, nx = cur ^ 1;
    const int kn = (ks < 31) ? ks + 1 : 31;  // static under full unroll
    A[nx][0]  = *(const short8*)(xpb + kn * 1024);
    A[nx][1]  = *(const short8*)(xpb + kn * 1024 + 512);
    BI[nx][0] = *(const short8*)(wpb + kn * 8192);
    BV[nx][0] = *(const short8*)(wpb + kn * 8192 + 512);
    BI[nx][1] = *(const short8*)(wpb + kn * 8192 + 1024);
    BV[nx][1] = *(const short8*)(wpb + kn * 8192 + 1536);
    ai[0][0] = mfma32(A[cur][0], BI[cur][0], ai[0][0]);
    ai[1][0] = mfma32(A[cur][1], BI[cur][0], ai[1][0]);
    ai[0][1] = mfma32(A[cur][0], BI[cur][1], ai[0][1]);
    ai[1][1] = mfma32(A[cur][1], BI[cur][1], ai[1][1]);
    av[0][0] = mfma32(A[cur][0], BV[cur][0], av[0][0]);
    av[1][0] = mfma32(A[cur][1], BV[cur][0], av[1][0]);
    av[0][1] = mfma32(A[cur][0], BV[cur][1], av[0][1]);
    av[1][1] = mfma32(A[cur][1], BV[cur][1], av[1][1]);
  }

  // ---- epilogue: per 32-row half, LDS round-trip into row-owning threads ----
  // C layout: col = wv*64 + nt*32 + l31, row_local = (q&3) + 8*(q>>2) + 4*h (+ mt*32)
  // LDS XOR swizzle: physical col' = col ^ ((row&7)<<2)  (bank-optimal for b128).
  // NOTE: scales/gamma/beta must be indexed by the LOGICAL column (seg*32+4j),
  // not the swizzled LDS offset — that was the R3 bug.
  const float inv_h = 1.0f / kH;
  float al[kIT];
#pragma unroll
  for (int i = 0; i < kIT; ++i) al[i] = alphas[t * kIT + i] * inv_h;

  const int row_r = tid >> 3;        // reader-owned row 0..31
  const int seg   = tid & 7;         // 8 lanes per row
  const int r4    = (row_r & 7) << 2;

  for (int mt = 0; mt < 2; ++mt) {
    __syncthreads();  // sAcc free (mt=1: previous sweep done)
#pragma unroll
    for (int nt = 0; nt < 2; ++nt)
#pragma unroll
      for (int q = 0; q < 16; ++q) {
        const int r   = (q & 3) + 8 * (q >> 2) + 4 * h;
        const int col = wv * 64 + nt * 32 + l31;
        sAcc[r * 256 + (col ^ ((r & 7) << 2))] = ai[mt][nt][q];
      }
    __syncthreads();

    float4 xt[8];
#pragma unroll
    for (int j = 0; j < 8; ++j) {
      xt[j] = *(const float4*)(sAcc + row_r * 256 + seg * 32 + ((4 * j) ^ r4));
#pragma unroll
      for (int i = 0; i < 4; ++i) xt[j][i] = fmaxf(xt[j][i], 0.f);
    }

#pragma unroll
    for (int it = 0; it < kIT; ++it) {
      float4 s4 = xt[0];
#pragma unroll
      for (int j = 1; j < 8; ++j) s4 += xt[j];
      float v = s4.x + s4.y + s4.z + s4.w;
      v += __shfl_xor(v, 1, 8);
      v += __shfl_xor(v, 2, 8);
      v += __shfl_xor(v, 4, 8);
      const float m = al[it] * v;   // alpha * mean
#pragma unroll
      for (int j = 0; j < 8; ++j)
#pragma unroll
        for (int i = 0; i < 4; ++i) xt[j][i] = fmaxf(xt[j][i] - m, 0.f);
    }

    __syncthreads();  // all ai reads done; reuse sAcc for av
#pragma unroll
    for (int nt = 0; nt < 2; ++nt)
#pragma unroll
      for (int q = 0; q < 16; ++q) {
        const int r   = (q & 3) + 8 * (q >> 2) + 4 * h;
        const int col = wv * 64 + nt * 32 + l31;
        sAcc[r * 256 + (col ^ ((r & 7) << 2))] = av[mt][nt][q];
      }
    __syncthreads();

    float4 res[8];
    float sum = 0.f, ssq = 0.f;
#pragma unroll
    for (int j = 0; j < 8; ++j) {
      const int cb = seg * 32 + ((4 * j) ^ r4);  // physical LDS offset
      const int lc = seg * 32 + 4 * j;           // logical column
      const float4 a4 = *(const float4*)(sAcc + row_r * 256 + cb);
      const float4 sc = *(const float4*)(scales + t * kH + lc);
      float4 s;
#pragma unroll
      for (int i = 0; i < 4; ++i) {
        s[i] = sc[i] * xt[j][i] * a4[i];
        sum += s[i];
        ssq += s[i] * s[i];
      }
      res[j] = s;
    }
    sum += __shfl_xor(sum, 1, 8);  ssq += __shfl_xor(ssq, 1, 8);
    sum += __shfl_xor(sum, 2, 8);  ssq += __shfl_xor(ssq, 2, 8);
    sum += __shfl_xor(sum, 4, 8);  ssq += __shfl_xor(ssq, 4, 8);
    const float mu  = sum * inv_h;
    const float var = ssq * inv_h - mu * mu;
    const float rs  = rsqrtf(var + kEPS);

#pragma unroll
    for (int j = 0; j < 8; ++j) {
      const int cb = seg * 32 + ((4 * j) ^ r4);
      const int lc = seg * 32 + 4 * j;
      const float4 g4 = *(const float4*)(gamma + t * kH + lc);
      const float4 b4 = *(const float4*)(beta + t * kH + lc);
      float4 o;
#pragma unroll
      for (int i = 0; i < 4; ++i) o[i] = (res[j][i] - mu) * rs * g4[i] + b4[i];
      *(float4*)(sAcc + row_r * 256 + cb) = o;
    }
    __syncthreads();

    // coalesced sweep: one wave per 8 rows, 1KB contiguous per instruction
#pragma unroll
    for (int r8 = 0; r8 < 8; ++r8) {
      const int rr = wv * 8 + r8;
      const int rb = (rr & 7) << 2;
      const float4 v = *(const float4*)(sAcc + rr * 256 + ((4 * lane) ^ rb));
      *(float4*)(out + (size_t)(slab * 64 + mt * 32 + rr) * (kT * kH) + t * kH + 4 * lane) = v;
    }
  }
}

extern "C" void kernel_launch(void* const* d_in, const int* in_sizes, int n_in,
                              void* d_out, int out_size, void* d_ws, size_t ws_size,
                              hipStream_t stream) {
  const float* x      = (const float*)d_in[0];
  const float* w_in   = (const float*)d_in[1];
  const float* w_val  = (const float*)d_in[2];
  const float* alphas = (const float*)d_in[3];
  const float* scales = (const float*)d_in[4];
  const float* gamma  = (const float*)d_in[5];
  const float* beta   = (const float*)d_in[6];
  float* out = (float*)d_out;

  // ws: xp 4MB (64*32*2 chunks * 1KB) | wp 16MB (32*32*16 chunks * 1KB)
  u16* xp = (u16*)d_ws;
  u16* wp = xp + (size_t)64 * 32 * 2 * 512;

  pack_kernel<<<5120, 256, 0, stream>>>(x, w_in, w_val, xp, wp);
  fused_kernel<<<kT * (kB / 64), 256, 0, stream>>>(xp, wp, alphas, scales,
                                                   gamma, beta, out);
}